// Round 8
// baseline (1523.086 us; speedup 1.0000x reference)
//
#include <hip/hip_runtime.h>

// GCN 2-layer forward on MI355X.
// Pipeline: decode edge_index -> CSR build -> agg128(x) -> gemm+b1+relu
//           -> agg256(h) -> gemm+b2.
// R1: agg inner loop batched by 8 (MLP fix); shfl-based single-block scan.
// R2: propagate-BEFORE-transform (A_hat(XW) == (A_hat X)W): layer-1 gathers
//     run over D=128 (half traffic); bias+ReLU fused into GEMM epilogue.
// R3: layer-1 agg processes 2 edges/iter (half-wave each, 16B/lane loads).
// R4: runtime int64/int32 edge_index detection + device-side decode to
//     canonical int32 (graph-capture-safe); OOB guards in histogram/fill.
// R5: nontemporal loads for single-use col/w streams in agg kernels.
// R6/R7: FROZEN — no kernel-side defect found in full audit; holding the
//     architecture until the first successful bench lands (remaining knobs
//     are regime-dependent and uninterpretable without counters).

#define DF 256  // GEMM output width (both layers)

// ---------------- utility ----------------
__global__ __launch_bounds__(256) void zero_i32(int* __restrict__ p, int n) {
  int i = blockIdx.x * blockDim.x + threadIdx.x;
  if (i < n) p[i] = 0;
}

// ---------------- edge_index dtype detection (int64 vs int32) ----------------
// Samples 1024 would-be int64 high words. All zero -> int64 layout (flag=1).
// Indices 2k+1 with k < n_logical/2 are in-bounds under BOTH interpretations.
__global__ __launch_bounds__(256) void detect_kernel(const int* __restrict__ ei32,
                                                     int n_logical,
                                                     int* __restrict__ flag) {
  __shared__ int s_nonzero;
  if (threadIdx.x == 0) s_nonzero = 0;
  __syncthreads();
  const int n_half = n_logical >> 1;
  int step = n_half / 1024;
  if (step < 1) step = 1;
  for (int k = threadIdx.x; k < 1024; k += 256) {
    long idx = (long)k * step;
    if (idx < n_half && ei32[2 * idx + 1] != 0) atomicOr(&s_nonzero, 1);
  }
  __syncthreads();
  if (threadIdx.x == 0) flag[0] = s_nonzero ? 0 : 1;  // 1 => int64
}

// ---------------- decode to canonical int32 ----------------
__global__ __launch_bounds__(256) void convert_kernel(const int* __restrict__ ei32,
                                                      const int* __restrict__ flag,
                                                      int* __restrict__ conv, int n) {
  int i = blockIdx.x * blockDim.x + threadIdx.x;
  if (i < n) conv[i] = flag[0] ? ei32[2 * (size_t)i] : ei32[i];
}

// ---------------- degree histogram ----------------
__global__ __launch_bounds__(256) void count_kernel(const int* __restrict__ dst,
                                                    int* __restrict__ cnt, int E, int n) {
  int i = blockIdx.x * blockDim.x + threadIdx.x;
  if (i < E) {
    int d = dst[i];
    if ((unsigned)d < (unsigned)n) atomicAdd(&cnt[d], 1);
  }
}

// ---------------- single-block exclusive scan over n counts ----------------
// 1024 threads, 4 elems/thread -> 4096/chunk; wave shfl-scan, ~4 barriers/chunk.
__global__ __launch_bounds__(1024) void scan_kernel(const int* __restrict__ cnt,
                                                    int* __restrict__ row_ptr, int n) {
  __shared__ int wsum[16];
  __shared__ int s_base;
  const int tid = threadIdx.x;
  const int lane = tid & 63;
  const int wid = tid >> 6;
  if (tid == 0) s_base = 0;
  __syncthreads();
  for (int start = 0; start < n; start += 4096) {
    const int i0 = start + tid * 4;
    int v[4];
#pragma unroll
    for (int u = 0; u < 4; ++u) v[u] = (i0 + u < n) ? cnt[i0 + u] : 0;
    const int tsum = v[0] + v[1] + v[2] + v[3];
    int sc = tsum;  // inclusive wave scan of per-thread sums
#pragma unroll
    for (int off = 1; off < 64; off <<= 1) {
      int t = __shfl_up(sc, off);
      if (lane >= off) sc += t;
    }
    if (lane == 63) wsum[wid] = sc;
    __syncthreads();
    if (wid == 0) {
      int ws = (lane < 16) ? wsum[lane] : 0;
#pragma unroll
      for (int off = 1; off < 16; off <<= 1) {
        int t = __shfl_up(ws, off);
        if (lane >= off) ws += t;
      }
      if (lane < 16) wsum[lane] = ws;  // inclusive wave-sum scan
    }
    __syncthreads();
    int base = s_base + (wid > 0 ? wsum[wid - 1] : 0) + (sc - tsum);
#pragma unroll
    for (int u = 0; u < 4; ++u) {
      if (i0 + u < n) row_ptr[i0 + u] = base;
      base += v[u];
    }
    __syncthreads();
    if (tid == 1023) s_base += wsum[15];
    __syncthreads();
  }
  if (tid == 0) row_ptr[n] = s_base;
}

// ---------------- dinv = rsqrt(deg+1), cursor = row_ptr copy ----------------
__global__ __launch_bounds__(256) void dinv_cursor_kernel(const int* __restrict__ cnt,
                                                          const int* __restrict__ row_ptr,
                                                          float* __restrict__ dinv,
                                                          int* __restrict__ cursor, int n) {
  int i = blockIdx.x * blockDim.x + threadIdx.x;
  if (i < n) {
    dinv[i] = rsqrtf((float)(cnt[i] + 1));  // +1: self-loop; always >= 1
    cursor[i] = row_ptr[i];
  }
}

// ---------------- CSR fill: col[] = src, w[] = dinv[src]*dinv[dst] ----------------
__global__ __launch_bounds__(256) void fill_kernel(const int* __restrict__ src,
                                                   const int* __restrict__ dst,
                                                   const float* __restrict__ dinv,
                                                   int* __restrict__ cursor,
                                                   int* __restrict__ col,
                                                   float* __restrict__ w, int E, int n) {
  int i = blockIdx.x * blockDim.x + threadIdx.x;
  if (i < E) {
    int s = src[i], d = dst[i];
    if ((unsigned)s < (unsigned)n && (unsigned)d < (unsigned)n) {
      int pos = atomicAdd(&cursor[d], 1);
      col[pos] = s;
      w[pos] = dinv[s] * dinv[d];
    }
  }
}

// ---------------- fp32 GEMM: out[M,256] = X[M,K] @ W[K,256] + b (opt ReLU) ----------------
// Block: 256 threads, 32-row x 256-col tile. Thread computes 8 rows x 4 cols.
// X tile staged in LDS (wave-broadcast reads, conflict-free); W streamed from
// L2. VALU-bound by design (no fp32 MFMA on CDNA4).
template <int K, bool RELU>
__global__ __launch_bounds__(256) void gemm_kernel(const float* __restrict__ X,
                                                   const float* __restrict__ W,
                                                   const float* __restrict__ bias,
                                                   float* __restrict__ out, int M) {
  __shared__ float xs[32][K];  // 16KB (K=128) or 32KB (K=256)
  const int t = threadIdx.x;
  const int row0 = blockIdx.x * 32;

  for (int i = t; i < 8 * K; i += 256) {  // 32*K/4 float4s
    int r = i / (K / 4);
    int kk = (i % (K / 4)) * 4;
    int gr = row0 + r;
    float4 v = make_float4(0.f, 0.f, 0.f, 0.f);
    if (gr < M) v = *(const float4*)&X[(size_t)gr * K + kk];
    *(float4*)&xs[r][kk] = v;
  }
  __syncthreads();

  const int c = (t & 63) * 4;   // column group (float4 along N)
  const int r0 = (t >> 6) * 8;  // 8 rows per thread
  float4 acc[8];
#pragma unroll
  for (int i = 0; i < 8; ++i) acc[i] = make_float4(0.f, 0.f, 0.f, 0.f);

  for (int k = 0; k < K; k += 4) {
    float4 wv[4];
#pragma unroll
    for (int j = 0; j < 4; ++j) wv[j] = *(const float4*)&W[(size_t)(k + j) * DF + c];
#pragma unroll
    for (int i = 0; i < 8; ++i) {
      float4 xv = *(const float4*)&xs[r0 + i][k];  // wave-broadcast LDS read
      acc[i].x = fmaf(xv.x, wv[0].x, acc[i].x);
      acc[i].y = fmaf(xv.x, wv[0].y, acc[i].y);
      acc[i].z = fmaf(xv.x, wv[0].z, acc[i].z);
      acc[i].w = fmaf(xv.x, wv[0].w, acc[i].w);
      acc[i].x = fmaf(xv.y, wv[1].x, acc[i].x);
      acc[i].y = fmaf(xv.y, wv[1].y, acc[i].y);
      acc[i].z = fmaf(xv.y, wv[1].z, acc[i].z);
      acc[i].w = fmaf(xv.y, wv[1].w, acc[i].w);
      acc[i].x = fmaf(xv.z, wv[2].x, acc[i].x);
      acc[i].y = fmaf(xv.z, wv[2].y, acc[i].y);
      acc[i].z = fmaf(xv.z, wv[2].z, acc[i].z);
      acc[i].w = fmaf(xv.z, wv[2].w, acc[i].w);
      acc[i].x = fmaf(xv.w, wv[3].x, acc[i].x);
      acc[i].y = fmaf(xv.w, wv[3].y, acc[i].y);
      acc[i].z = fmaf(xv.w, wv[3].z, acc[i].z);
      acc[i].w = fmaf(xv.w, wv[3].w, acc[i].w);
    }
  }

  const float4 bv = *(const float4*)&bias[c];
#pragma unroll
  for (int i = 0; i < 8; ++i) {
    int gr = row0 + r0 + i;
    if (gr < M) {
      float4 r;
      r.x = acc[i].x + bv.x;
      r.y = acc[i].y + bv.y;
      r.z = acc[i].z + bv.z;
      r.w = acc[i].w + bv.w;
      if (RELU) {
        r.x = fmaxf(r.x, 0.f);
        r.y = fmaxf(r.y, 0.f);
        r.z = fmaxf(r.z, 0.f);
        r.w = fmaxf(r.w, 0.f);
      }
      *(float4*)&out[(size_t)gr * DF + c] = r;
    }
  }
}

// ---------------- CSR aggregation, D=256: one wave per node, 1 edge/iter ----------------
// Lane l owns features [4l,4l+4): 64 lanes x 16B = full 1KB row per gather.
// col/w loaded 64-wide NONTEMPORAL (single-use stream; keep L2 for h),
// broadcast via shfl; batch of 8 -> 8 outstanding gathers.
__global__ __launch_bounds__(256) void agg256_kernel(const float* __restrict__ h,
                                                     const int* __restrict__ row_ptr,
                                                     const int* __restrict__ col,
                                                     const float* __restrict__ w,
                                                     const float* __restrict__ dinv,
                                                     float* __restrict__ out, int n) {
  int wid = (blockIdx.x * blockDim.x + threadIdx.x) >> 6;  // node = wave id
  int lane = threadIdx.x & 63;
  if (wid >= n) return;
  int start = row_ptr[wid];
  int end = row_ptr[wid + 1];
  const int foff = lane * 4;

  float4 acc = make_float4(0.f, 0.f, 0.f, 0.f);
  for (int base = start; base < end; base += 64) {
    int e = base + lane;
    int ce = 0;
    float we = 0.f;
    if (e < end) {
      ce = __builtin_nontemporal_load(&col[e]);
      we = __builtin_nontemporal_load(&w[e]);
    }
    int m = end - base;
    if (m > 64) m = 64;
    int j = 0;
    for (; j + 8 <= m; j += 8) {
      float4 hv[8];
      float ww[8];
#pragma unroll
      for (int u = 0; u < 8; ++u) {
        int s = __shfl(ce, j + u);
        ww[u] = __shfl(we, j + u);
        hv[u] = *(const float4*)&h[(size_t)s * 256 + foff];
      }
#pragma unroll
      for (int u = 0; u < 8; ++u) {
        acc.x = fmaf(hv[u].x, ww[u], acc.x);
        acc.y = fmaf(hv[u].y, ww[u], acc.y);
        acc.z = fmaf(hv[u].z, ww[u], acc.z);
        acc.w = fmaf(hv[u].w, ww[u], acc.w);
      }
    }
    for (; j < m; ++j) {
      int s = __shfl(ce, j);
      float ww = __shfl(we, j);
      float4 hv = *(const float4*)&h[(size_t)s * 256 + foff];
      acc.x = fmaf(hv.x, ww, acc.x);
      acc.y = fmaf(hv.y, ww, acc.y);
      acc.z = fmaf(hv.z, ww, acc.z);
      acc.w = fmaf(hv.w, ww, acc.w);
    }
  }
  // self-loop
  float di = dinv[wid];
  float sw = di * di;
  float4 own = *(const float4*)&h[(size_t)wid * 256 + foff];
  acc.x = fmaf(own.x, sw, acc.x);
  acc.y = fmaf(own.y, sw, acc.y);
  acc.z = fmaf(own.z, sw, acc.z);
  acc.w = fmaf(own.w, sw, acc.w);
  *(float4*)&out[(size_t)wid * 256 + foff] = acc;
}

// ---------------- CSR aggregation, D=128: one wave per node, 2 edges/iter ----------------
// Half-wave per edge: lanes 0-31 take edge 2j, lanes 32-63 take edge 2j+1.
// Each lane loads 16B (32 lanes x 16B = full 512B row). Batch of 8 iters
// covers 16 edges with 8 outstanding gathers. Cross-half __shfl_xor(32)
// reduction at the end; half 0 stores. (R3; nt col/w loads R5)
__global__ __launch_bounds__(256) void agg128_kernel(const float* __restrict__ h,
                                                     const int* __restrict__ row_ptr,
                                                     const int* __restrict__ col,
                                                     const float* __restrict__ w,
                                                     const float* __restrict__ dinv,
                                                     float* __restrict__ out, int n) {
  int wid = (blockIdx.x * blockDim.x + threadIdx.x) >> 6;  // node = wave id
  int lane = threadIdx.x & 63;
  if (wid >= n) return;
  int start = row_ptr[wid];
  int end = row_ptr[wid + 1];
  const int half = lane >> 5;         // 0 or 1
  const int foff = (lane & 31) * 4;   // feature offset within the 128-row

  float4 acc = make_float4(0.f, 0.f, 0.f, 0.f);
  for (int base = start; base < end; base += 64) {
    int e = base + lane;
    int ce = 0;
    float we = 0.f;
    if (e < end) {
      ce = __builtin_nontemporal_load(&col[e]);
      we = __builtin_nontemporal_load(&w[e]);
    }
    int m = end - base;
    if (m > 64) m = 64;
    int j = 0;
    for (; j + 16 <= m; j += 16) {  // 8 iters x 2 edges
      float4 hv[8];
      float ww[8];
#pragma unroll
      for (int u = 0; u < 8; ++u) {
        int idx = j + 2 * u + half;
        int s = __shfl(ce, idx);
        ww[u] = __shfl(we, idx);
        hv[u] = *(const float4*)&h[(size_t)s * 128 + foff];
      }
#pragma unroll
      for (int u = 0; u < 8; ++u) {
        acc.x = fmaf(hv[u].x, ww[u], acc.x);
        acc.y = fmaf(hv[u].y, ww[u], acc.y);
        acc.z = fmaf(hv[u].z, ww[u], acc.z);
        acc.w = fmaf(hv[u].w, ww[u], acc.w);
      }
    }
    for (; j + 2 <= m; j += 2) {  // leftover pairs
      int idx = j + half;
      int s = __shfl(ce, idx);
      float ww = __shfl(we, idx);
      float4 hv = *(const float4*)&h[(size_t)s * 128 + foff];
      acc.x = fmaf(hv.x, ww, acc.x);
      acc.y = fmaf(hv.y, ww, acc.y);
      acc.z = fmaf(hv.z, ww, acc.z);
      acc.w = fmaf(hv.w, ww, acc.w);
    }
    if (j < m) {  // single leftover edge: half 0 only
      int s = __shfl(ce, j);
      float ww = __shfl(we, j);
      if (half == 0) {
        float4 hv = *(const float4*)&h[(size_t)s * 128 + foff];
        acc.x = fmaf(hv.x, ww, acc.x);
        acc.y = fmaf(hv.y, ww, acc.y);
        acc.z = fmaf(hv.z, ww, acc.z);
        acc.w = fmaf(hv.w, ww, acc.w);
      }
    }
  }
  // combine the two half-wave partial sums (lane l <-> lane l^32 hold same features)
  acc.x += __shfl_xor(acc.x, 32);
  acc.y += __shfl_xor(acc.y, 32);
  acc.z += __shfl_xor(acc.z, 32);
  acc.w += __shfl_xor(acc.w, 32);
  if (half == 0) {
    float di = dinv[wid];
    float sw = di * di;
    float4 own = *(const float4*)&h[(size_t)wid * 128 + foff];
    acc.x = fmaf(own.x, sw, acc.x);
    acc.y = fmaf(own.y, sw, acc.y);
    acc.z = fmaf(own.z, sw, acc.z);
    acc.w = fmaf(own.w, sw, acc.w);
    *(float4*)&out[(size_t)wid * 128 + foff] = acc;
  }
}

// ---------------- launch ----------------
extern "C" void kernel_launch(void* const* d_in, const int* in_sizes, int n_in,
                              void* d_out, int out_size, void* d_ws, size_t ws_size,
                              hipStream_t stream) {
  const float* x = (const float*)d_in[0];
  const int* ei = (const int*)d_in[1];  // raw words; dtype resolved on-device (R4)
  const float* W1 = (const float*)d_in[2];
  const float* b1 = (const float*)d_in[3];
  const float* W2 = (const float*)d_in[4];
  const float* b2 = (const float*)d_in[5];
  float* out = (float*)d_out;

  const int N = in_sizes[0] / 128;   // 100000
  const int NE2 = in_sizes[1];       // 2*E logical int elements
  const int E = NE2 / 2;             // 3200000

  // workspace carve (256B aligned); total ~129.3MB
  char* p = (char*)d_ws;
  auto carve = [&](size_t bytes) {
    void* q = (void*)p;
    p += (bytes + 255) & ~(size_t)255;
    return q;
  };
  int* flag = (int*)carve(4);
  int* cnt = (int*)carve((size_t)N * 4);
  int* row_ptr = (int*)carve((size_t)(N + 1) * 4);
  int* cursor = (int*)carve((size_t)N * 4);
  float* dinv = (float*)carve((size_t)N * 4);
  int* col = (int*)carve((size_t)E * 4);
  float* w = (float*)carve((size_t)E * 4);
  float* buf = (float*)carve((size_t)N * DF * 4);  // 102.4MB; serves ax & ah
  // decoded edge_index aliases buf's head (dead until agg128 runs)
  int* conv = (int*)buf;
  const int* src = conv;
  const int* dst = conv + E;

  // ---- decode edge_index (int64 vs int32, device-side) ----
  detect_kernel<<<1, 256, 0, stream>>>(ei, NE2, flag);
  convert_kernel<<<(NE2 + 255) / 256, 256, 0, stream>>>(ei, flag, conv, NE2);

  // ---- CSR build (shared by both layers) ----
  zero_i32<<<(N + 255) / 256, 256, 0, stream>>>(cnt, N);
  count_kernel<<<(E + 255) / 256, 256, 0, stream>>>(dst, cnt, E, N);
  scan_kernel<<<1, 1024, 0, stream>>>(cnt, row_ptr, N);
  dinv_cursor_kernel<<<(N + 255) / 256, 256, 0, stream>>>(cnt, row_ptr, dinv, cursor, N);
  fill_kernel<<<(E + 255) / 256, 256, 0, stream>>>(src, dst, dinv, cursor, col, w, E, N);

  const int agg_blocks = (N * 64 + 255) / 256;  // one wave per node

  // ---- layer 1: ax = A_hat x ; h = relu(ax @ W1 + b1) -> d_out ----
  agg128_kernel<<<agg_blocks, 256, 0, stream>>>(x, row_ptr, col, w, dinv, buf, N);
  gemm_kernel<128, true><<<(N + 31) / 32, 256, 0, stream>>>(buf, W1, b1, out, N);

  // ---- layer 2: ah = A_hat h ; out = ah @ W2 + b2 -> d_out ----
  agg256_kernel<<<agg_blocks, 256, 0, stream>>>(out, row_ptr, col, w, dinv, buf, N);
  gemm_kernel<256, false><<<(N + 31) / 32, 256, 0, stream>>>(buf, W2, b2, out, N);
}

// Round 9
// 1415.430 us; speedup vs baseline: 1.0761x; 1.0761x over previous
//
#include <hip/hip_runtime.h>

// GCN 2-layer forward on MI355X.
// Pipeline: decode edge_index -> CSR build -> agg128(x) -> gemm+b1+relu
//           -> agg256(h) -> gemm+b2.
// R2: propagate-BEFORE-transform; bias+ReLU fused into GEMM epilogue.
// R3: agg128 half-wave-per-edge (16B/lane loads).
// R4: int64/int32 edge_index decode on device; OOB guards.
// R5: nontemporal loads for the single-use edge stream.
// R8 (first bench: 1523us; agg256=474us, VALUBusy 8.8%, FETCH 1.65GB vs
//     3.28GB logical -> L2 absorbs ~50%; regime ambiguous latency-vs-L3BW):
//     batch depth 8->16 (agg256) / 16->32 edges (agg128) to double in-flight
//     gather bytes; packed int2 (col,w) edge array (1x8B scatter in fill,
//     1x8B nt load in agg). A/B discriminates the regime.

#define DF 256  // GEMM output width (both layers)

// ---------------- utility ----------------
__global__ __launch_bounds__(256) void zero_i32(int* __restrict__ p, int n) {
  int i = blockIdx.x * blockDim.x + threadIdx.x;
  if (i < n) p[i] = 0;
}

// ---------------- edge_index dtype detection (int64 vs int32) ----------------
__global__ __launch_bounds__(256) void detect_kernel(const int* __restrict__ ei32,
                                                     int n_logical,
                                                     int* __restrict__ flag) {
  __shared__ int s_nonzero;
  if (threadIdx.x == 0) s_nonzero = 0;
  __syncthreads();
  const int n_half = n_logical >> 1;
  int step = n_half / 1024;
  if (step < 1) step = 1;
  for (int k = threadIdx.x; k < 1024; k += 256) {
    long idx = (long)k * step;
    if (idx < n_half && ei32[2 * idx + 1] != 0) atomicOr(&s_nonzero, 1);
  }
  __syncthreads();
  if (threadIdx.x == 0) flag[0] = s_nonzero ? 0 : 1;  // 1 => int64
}

// ---------------- decode to canonical int32 ----------------
__global__ __launch_bounds__(256) void convert_kernel(const int* __restrict__ ei32,
                                                      const int* __restrict__ flag,
                                                      int* __restrict__ conv, int n) {
  int i = blockIdx.x * blockDim.x + threadIdx.x;
  if (i < n) conv[i] = flag[0] ? ei32[2 * (size_t)i] : ei32[i];
}

// ---------------- degree histogram ----------------
__global__ __launch_bounds__(256) void count_kernel(const int* __restrict__ dst,
                                                    int* __restrict__ cnt, int E, int n) {
  int i = blockIdx.x * blockDim.x + threadIdx.x;
  if (i < E) {
    int d = dst[i];
    if ((unsigned)d < (unsigned)n) atomicAdd(&cnt[d], 1);
  }
}

// ---------------- single-block exclusive scan over n counts ----------------
__global__ __launch_bounds__(1024) void scan_kernel(const int* __restrict__ cnt,
                                                    int* __restrict__ row_ptr, int n) {
  __shared__ int wsum[16];
  __shared__ int s_base;
  const int tid = threadIdx.x;
  const int lane = tid & 63;
  const int wid = tid >> 6;
  if (tid == 0) s_base = 0;
  __syncthreads();
  for (int start = 0; start < n; start += 4096) {
    const int i0 = start + tid * 4;
    int v[4];
#pragma unroll
    for (int u = 0; u < 4; ++u) v[u] = (i0 + u < n) ? cnt[i0 + u] : 0;
    const int tsum = v[0] + v[1] + v[2] + v[3];
    int sc = tsum;  // inclusive wave scan of per-thread sums
#pragma unroll
    for (int off = 1; off < 64; off <<= 1) {
      int t = __shfl_up(sc, off);
      if (lane >= off) sc += t;
    }
    if (lane == 63) wsum[wid] = sc;
    __syncthreads();
    if (wid == 0) {
      int ws = (lane < 16) ? wsum[lane] : 0;
#pragma unroll
      for (int off = 1; off < 16; off <<= 1) {
        int t = __shfl_up(ws, off);
        if (lane >= off) ws += t;
      }
      if (lane < 16) wsum[lane] = ws;  // inclusive wave-sum scan
    }
    __syncthreads();
    int base = s_base + (wid > 0 ? wsum[wid - 1] : 0) + (sc - tsum);
#pragma unroll
    for (int u = 0; u < 4; ++u) {
      if (i0 + u < n) row_ptr[i0 + u] = base;
      base += v[u];
    }
    __syncthreads();
    if (tid == 1023) s_base += wsum[15];
    __syncthreads();
  }
  if (tid == 0) row_ptr[n] = s_base;
}

// ---------------- dinv = rsqrt(deg+1), cursor = row_ptr copy ----------------
__global__ __launch_bounds__(256) void dinv_cursor_kernel(const int* __restrict__ cnt,
                                                          const int* __restrict__ row_ptr,
                                                          float* __restrict__ dinv,
                                                          int* __restrict__ cursor, int n) {
  int i = blockIdx.x * blockDim.x + threadIdx.x;
  if (i < n) {
    dinv[i] = rsqrtf((float)(cnt[i] + 1));  // +1: self-loop; always >= 1
    cursor[i] = row_ptr[i];
  }
}

// ---------------- CSR fill: edge[] = {src, dinv[src]*dinv[dst]} packed ----------------
__global__ __launch_bounds__(256) void fill_kernel(const int* __restrict__ src,
                                                   const int* __restrict__ dst,
                                                   const float* __restrict__ dinv,
                                                   int* __restrict__ cursor,
                                                   int2* __restrict__ edge, int E, int n) {
  int i = blockIdx.x * blockDim.x + threadIdx.x;
  if (i < E) {
    int s = src[i], d = dst[i];
    if ((unsigned)s < (unsigned)n && (unsigned)d < (unsigned)n) {
      int pos = atomicAdd(&cursor[d], 1);
      edge[pos] = make_int2(s, __float_as_int(dinv[s] * dinv[d]));  // one 8B scatter
    }
  }
}

// ---------------- fp32 GEMM: out[M,256] = X[M,K] @ W[K,256] + b (opt ReLU) ----------------
template <int K, bool RELU>
__global__ __launch_bounds__(256) void gemm_kernel(const float* __restrict__ X,
                                                   const float* __restrict__ W,
                                                   const float* __restrict__ bias,
                                                   float* __restrict__ out, int M) {
  __shared__ float xs[32][K];  // 16KB (K=128) or 32KB (K=256)
  const int t = threadIdx.x;
  const int row0 = blockIdx.x * 32;

  for (int i = t; i < 8 * K; i += 256) {  // 32*K/4 float4s
    int r = i / (K / 4);
    int kk = (i % (K / 4)) * 4;
    int gr = row0 + r;
    float4 v = make_float4(0.f, 0.f, 0.f, 0.f);
    if (gr < M) v = *(const float4*)&X[(size_t)gr * K + kk];
    *(float4*)&xs[r][kk] = v;
  }
  __syncthreads();

  const int c = (t & 63) * 4;   // column group (float4 along N)
  const int r0 = (t >> 6) * 8;  // 8 rows per thread
  float4 acc[8];
#pragma unroll
  for (int i = 0; i < 8; ++i) acc[i] = make_float4(0.f, 0.f, 0.f, 0.f);

  for (int k = 0; k < K; k += 4) {
    float4 wv[4];
#pragma unroll
    for (int j = 0; j < 4; ++j) wv[j] = *(const float4*)&W[(size_t)(k + j) * DF + c];
#pragma unroll
    for (int i = 0; i < 8; ++i) {
      float4 xv = *(const float4*)&xs[r0 + i][k];  // wave-broadcast LDS read
      acc[i].x = fmaf(xv.x, wv[0].x, acc[i].x);
      acc[i].y = fmaf(xv.x, wv[0].y, acc[i].y);
      acc[i].z = fmaf(xv.x, wv[0].z, acc[i].z);
      acc[i].w = fmaf(xv.x, wv[0].w, acc[i].w);
      acc[i].x = fmaf(xv.y, wv[1].x, acc[i].x);
      acc[i].y = fmaf(xv.y, wv[1].y, acc[i].y);
      acc[i].z = fmaf(xv.y, wv[1].z, acc[i].z);
      acc[i].w = fmaf(xv.y, wv[1].w, acc[i].w);
      acc[i].x = fmaf(xv.z, wv[2].x, acc[i].x);
      acc[i].y = fmaf(xv.z, wv[2].y, acc[i].y);
      acc[i].z = fmaf(xv.z, wv[2].z, acc[i].z);
      acc[i].w = fmaf(xv.z, wv[2].w, acc[i].w);
      acc[i].x = fmaf(xv.w, wv[3].x, acc[i].x);
      acc[i].y = fmaf(xv.w, wv[3].y, acc[i].y);
      acc[i].z = fmaf(xv.w, wv[3].z, acc[i].z);
      acc[i].w = fmaf(xv.w, wv[3].w, acc[i].w);
    }
  }

  const float4 bv = *(const float4*)&bias[c];
#pragma unroll
  for (int i = 0; i < 8; ++i) {
    int gr = row0 + r0 + i;
    if (gr < M) {
      float4 r;
      r.x = acc[i].x + bv.x;
      r.y = acc[i].y + bv.y;
      r.z = acc[i].z + bv.z;
      r.w = acc[i].w + bv.w;
      if (RELU) {
        r.x = fmaxf(r.x, 0.f);
        r.y = fmaxf(r.y, 0.f);
        r.z = fmaxf(r.z, 0.f);
        r.w = fmaxf(r.w, 0.f);
      }
      *(float4*)&out[(size_t)gr * DF + c] = r;
    }
  }
}

// ---------------- CSR aggregation, D=256: one wave per node, batch-16 ----------------
__global__ __launch_bounds__(256) void agg256_kernel(const float* __restrict__ h,
                                                     const int* __restrict__ row_ptr,
                                                     const int2* __restrict__ edge,
                                                     const float* __restrict__ dinv,
                                                     float* __restrict__ out, int n) {
  int wid = (blockIdx.x * blockDim.x + threadIdx.x) >> 6;  // node = wave id
  int lane = threadIdx.x & 63;
  if (wid >= n) return;
  int start = row_ptr[wid];
  int end = row_ptr[wid + 1];
  const int foff = lane * 4;

  float4 acc = make_float4(0.f, 0.f, 0.f, 0.f);
  for (int base = start; base < end; base += 64) {
    int e = base + lane;
    int ce = 0;
    float we = 0.f;
    if (e < end) {
      long long ev = __builtin_nontemporal_load((const long long*)edge + e);
      ce = (int)(ev & 0xffffffffLL);
      we = __int_as_float((int)(ev >> 32));
    }
    int m = end - base;
    if (m > 64) m = 64;
    int j = 0;
    for (; j + 16 <= m; j += 16) {  // 16 outstanding 1KB gathers (R8)
      float4 hv[16];
      float ww[16];
#pragma unroll
      for (int u = 0; u < 16; ++u) {
        int s = __shfl(ce, j + u);
        ww[u] = __shfl(we, j + u);
        hv[u] = *(const float4*)&h[(size_t)s * 256 + foff];
      }
#pragma unroll
      for (int u = 0; u < 16; ++u) {
        acc.x = fmaf(hv[u].x, ww[u], acc.x);
        acc.y = fmaf(hv[u].y, ww[u], acc.y);
        acc.z = fmaf(hv[u].z, ww[u], acc.z);
        acc.w = fmaf(hv[u].w, ww[u], acc.w);
      }
    }
    for (; j + 8 <= m; j += 8) {
      float4 hv[8];
      float ww[8];
#pragma unroll
      for (int u = 0; u < 8; ++u) {
        int s = __shfl(ce, j + u);
        ww[u] = __shfl(we, j + u);
        hv[u] = *(const float4*)&h[(size_t)s * 256 + foff];
      }
#pragma unroll
      for (int u = 0; u < 8; ++u) {
        acc.x = fmaf(hv[u].x, ww[u], acc.x);
        acc.y = fmaf(hv[u].y, ww[u], acc.y);
        acc.z = fmaf(hv[u].z, ww[u], acc.z);
        acc.w = fmaf(hv[u].w, ww[u], acc.w);
      }
    }
    for (; j < m; ++j) {
      int s = __shfl(ce, j);
      float ww = __shfl(we, j);
      float4 hv = *(const float4*)&h[(size_t)s * 256 + foff];
      acc.x = fmaf(hv.x, ww, acc.x);
      acc.y = fmaf(hv.y, ww, acc.y);
      acc.z = fmaf(hv.z, ww, acc.z);
      acc.w = fmaf(hv.w, ww, acc.w);
    }
  }
  // self-loop
  float di = dinv[wid];
  float sw = di * di;
  float4 own = *(const float4*)&h[(size_t)wid * 256 + foff];
  acc.x = fmaf(own.x, sw, acc.x);
  acc.y = fmaf(own.y, sw, acc.y);
  acc.z = fmaf(own.z, sw, acc.z);
  acc.w = fmaf(own.w, sw, acc.w);
  *(float4*)&out[(size_t)wid * 256 + foff] = acc;
}

// ---------------- CSR aggregation, D=128: half-wave per edge, batch-32 ----------------
__global__ __launch_bounds__(256) void agg128_kernel(const float* __restrict__ h,
                                                     const int* __restrict__ row_ptr,
                                                     const int2* __restrict__ edge,
                                                     const float* __restrict__ dinv,
                                                     float* __restrict__ out, int n) {
  int wid = (blockIdx.x * blockDim.x + threadIdx.x) >> 6;  // node = wave id
  int lane = threadIdx.x & 63;
  if (wid >= n) return;
  int start = row_ptr[wid];
  int end = row_ptr[wid + 1];
  const int half = lane >> 5;         // 0 or 1
  const int foff = (lane & 31) * 4;   // feature offset within the 128-row

  float4 acc = make_float4(0.f, 0.f, 0.f, 0.f);
  for (int base = start; base < end; base += 64) {
    int e = base + lane;
    int ce = 0;
    float we = 0.f;
    if (e < end) {
      long long ev = __builtin_nontemporal_load((const long long*)edge + e);
      ce = (int)(ev & 0xffffffffLL);
      we = __int_as_float((int)(ev >> 32));
    }
    int m = end - base;
    if (m > 64) m = 64;
    int j = 0;
    for (; j + 32 <= m; j += 32) {  // 16 iters x 2 edges -> 16 outstanding (R8)
      float4 hv[16];
      float ww[16];
#pragma unroll
      for (int u = 0; u < 16; ++u) {
        int idx = j + 2 * u + half;
        int s = __shfl(ce, idx);
        ww[u] = __shfl(we, idx);
        hv[u] = *(const float4*)&h[(size_t)s * 128 + foff];
      }
#pragma unroll
      for (int u = 0; u < 16; ++u) {
        acc.x = fmaf(hv[u].x, ww[u], acc.x);
        acc.y = fmaf(hv[u].y, ww[u], acc.y);
        acc.z = fmaf(hv[u].z, ww[u], acc.z);
        acc.w = fmaf(hv[u].w, ww[u], acc.w);
      }
    }
    for (; j + 16 <= m; j += 16) {  // 8 iters x 2 edges
      float4 hv[8];
      float ww[8];
#pragma unroll
      for (int u = 0; u < 8; ++u) {
        int idx = j + 2 * u + half;
        int s = __shfl(ce, idx);
        ww[u] = __shfl(we, idx);
        hv[u] = *(const float4*)&h[(size_t)s * 128 + foff];
      }
#pragma unroll
      for (int u = 0; u < 8; ++u) {
        acc.x = fmaf(hv[u].x, ww[u], acc.x);
        acc.y = fmaf(hv[u].y, ww[u], acc.y);
        acc.z = fmaf(hv[u].z, ww[u], acc.z);
        acc.w = fmaf(hv[u].w, ww[u], acc.w);
      }
    }
    for (; j + 2 <= m; j += 2) {  // leftover pairs
      int idx = j + half;
      int s = __shfl(ce, idx);
      float ww = __shfl(we, idx);
      float4 hv = *(const float4*)&h[(size_t)s * 128 + foff];
      acc.x = fmaf(hv.x, ww, acc.x);
      acc.y = fmaf(hv.y, ww, acc.y);
      acc.z = fmaf(hv.z, ww, acc.z);
      acc.w = fmaf(hv.w, ww, acc.w);
    }
    if (j < m) {  // single leftover edge: half 0 only
      int s = __shfl(ce, j);
      float ww = __shfl(we, j);
      if (half == 0) {
        float4 hv = *(const float4*)&h[(size_t)s * 128 + foff];
        acc.x = fmaf(hv.x, ww, acc.x);
        acc.y = fmaf(hv.y, ww, acc.y);
        acc.z = fmaf(hv.z, ww, acc.z);
        acc.w = fmaf(hv.w, ww, acc.w);
      }
    }
  }
  // combine the two half-wave partial sums
  acc.x += __shfl_xor(acc.x, 32);
  acc.y += __shfl_xor(acc.y, 32);
  acc.z += __shfl_xor(acc.z, 32);
  acc.w += __shfl_xor(acc.w, 32);
  if (half == 0) {
    float di = dinv[wid];
    float sw = di * di;
    float4 own = *(const float4*)&h[(size_t)wid * 128 + foff];
    acc.x = fmaf(own.x, sw, acc.x);
    acc.y = fmaf(own.y, sw, acc.y);
    acc.z = fmaf(own.z, sw, acc.z);
    acc.w = fmaf(own.w, sw, acc.w);
    *(float4*)&out[(size_t)wid * 128 + foff] = acc;
  }
}

// ---------------- launch ----------------
extern "C" void kernel_launch(void* const* d_in, const int* in_sizes, int n_in,
                              void* d_out, int out_size, void* d_ws, size_t ws_size,
                              hipStream_t stream) {
  const float* x = (const float*)d_in[0];
  const int* ei = (const int*)d_in[1];  // raw words; dtype resolved on-device (R4)
  const float* W1 = (const float*)d_in[2];
  const float* b1 = (const float*)d_in[3];
  const float* W2 = (const float*)d_in[4];
  const float* b2 = (const float*)d_in[5];
  float* out = (float*)d_out;

  const int N = in_sizes[0] / 128;   // 100000
  const int NE2 = in_sizes[1];       // 2*E logical int elements
  const int E = NE2 / 2;             // 3200000

  // workspace carve (256B aligned); total ~129.3MB
  char* p = (char*)d_ws;
  auto carve = [&](size_t bytes) {
    void* q = (void*)p;
    p += (bytes + 255) & ~(size_t)255;
    return q;
  };
  int* flag = (int*)carve(4);
  int* cnt = (int*)carve((size_t)N * 4);
  int* row_ptr = (int*)carve((size_t)(N + 1) * 4);
  int* cursor = (int*)carve((size_t)N * 4);
  float* dinv = (float*)carve((size_t)N * 4);
  int2* edge = (int2*)carve((size_t)E * 8);  // packed (col, w)
  float* buf = (float*)carve((size_t)N * DF * 4);  // 102.4MB; serves ax & ah
  // decoded edge_index aliases buf's head (dead until agg128 runs)
  int* conv = (int*)buf;
  const int* src = conv;
  const int* dst = conv + E;

  // ---- decode edge_index (int64 vs int32, device-side) ----
  detect_kernel<<<1, 256, 0, stream>>>(ei, NE2, flag);
  convert_kernel<<<(NE2 + 255) / 256, 256, 0, stream>>>(ei, flag, conv, NE2);

  // ---- CSR build (shared by both layers) ----
  zero_i32<<<(N + 255) / 256, 256, 0, stream>>>(cnt, N);
  count_kernel<<<(E + 255) / 256, 256, 0, stream>>>(dst, cnt, E, N);
  scan_kernel<<<1, 1024, 0, stream>>>(cnt, row_ptr, N);
  dinv_cursor_kernel<<<(N + 255) / 256, 256, 0, stream>>>(cnt, row_ptr, dinv, cursor, N);
  fill_kernel<<<(E + 255) / 256, 256, 0, stream>>>(src, dst, dinv, cursor, edge, E, N);

  const int agg_blocks = (N * 64 + 255) / 256;  // one wave per node

  // ---- layer 1: ax = A_hat x ; h = relu(ax @ W1 + b1) -> d_out ----
  agg128_kernel<<<agg_blocks, 256, 0, stream>>>(x, row_ptr, edge, dinv, buf, N);
  gemm_kernel<128, true><<<(N + 31) / 32, 256, 0, stream>>>(buf, W1, b1, out, N);

  // ---- layer 2: ah = A_hat h ; out = ah @ W2 + b2 -> d_out ----
  agg256_kernel<<<agg_blocks, 256, 0, stream>>>(out, row_ptr, edge, dinv, buf, N);
  gemm_kernel<256, false><<<(N + 31) / 32, 256, 0, stream>>>(buf, W2, b2, out, N);
}